// Round 9
// baseline (344.550 us; speedup 1.0000x reference)
//
#include <hip/hip_runtime.h>
#include <hip/hip_bf16.h>

#define B 4
#define S 2048
#define H 16
#define D 64
#define HID 1024

typedef __hip_bfloat16 bf16;
typedef __attribute__((ext_vector_type(8))) short bf16x8;
typedef __attribute__((ext_vector_type(4))) short bf16x4;
typedef __attribute__((ext_vector_type(4))) float f32x4;

static __device__ __forceinline__ float b2f(bf16 v) { return __bfloat162float(v); }
static __device__ __forceinline__ float ldf(const float* p, size_t i) { return p[i]; }
static __device__ __forceinline__ float ldf(const bf16* p, size_t i) { return b2f(p[i]); }

static __device__ __forceinline__ unsigned pkbf(float a, float b) {
    union { bf16 h; unsigned short u; } ua, ub;
    ua.h = __float2bfloat16(a);
    ub.h = __float2bfloat16(b);
    return (unsigned)ua.u | ((unsigned)ub.u << 16);
}

// ---------------------------------------------------------------------------
// Kernel 0: dtype detector (proven R2-R8). flags[i]=1 -> fp32.
// ---------------------------------------------------------------------------
__global__ __launch_bounds__(256) void detect_kernel(
    const void* p0, const void* p1, const void* p2, const void* p3,
    const void* p4, const void* p5, const void* p6, const void* p7,
    const void* p8, int* flags)
{
    __shared__ int cnt;
    const void* ps[9] = {p0, p1, p2, p3, p4, p5, p6, p7, p8};
    const int   ns[9] = {B * S * D, D * HID, HID, D * HID, HID,
                         D * HID, HID, HID * D, D};
    const int i = blockIdx.x;
    const bf16* p = (const bf16*)ps[i];
    int n = ns[i];
    if (n > 2048) n = 2048;
    if (threadIdx.x == 0) cnt = 0;
    __syncthreads();
    int wild = 0;
    for (int t = threadIdx.x; t < n; t += 256) {
        float f = b2f(p[t]);
        if (!(f == f) || fabsf(f) > 1e4f) wild++;
    }
    if (wild) atomicAdd(&cnt, wild);
    __syncthreads();
    if (threadIdx.x == 0) flags[i] = (cnt >= 2) ? 1 : 0;
}

// ---------------------------------------------------------------------------
// Kernel 1: QKV projection as MFMA GEMM (unchanged from R8).
// Q,K stored [B][H][S][D]; V stored TRANSPOSED [B][H][D][S].
// ---------------------------------------------------------------------------
#define QSTR 72

template <typename T>
static __device__ __forceinline__ void qkv_mfma_body(
    const T* __restrict__ x,
    const T* __restrict__ Wq, const T* __restrict__ bq,
    const T* __restrict__ Wk, const T* __restrict__ bk,
    const T* __restrict__ Wv, const T* __restrict__ bv,
    bf16* __restrict__ q, bf16* __restrict__ k, bf16* __restrict__ v,
    bf16* Xs, bf16* Wt, float* bs)
{
    const int tid = threadIdx.x;
    const int mat = blockIdx.y >> 3;
    const int N0  = (blockIdx.y & 7) * 128;
    const int m0  = blockIdx.x * 128;

    const T* W    = (mat == 0) ? Wq : (mat == 1) ? Wk : Wv;
    const T* bias = (mat == 0) ? bq : (mat == 1) ? bk : bv;
    bf16*    dst  = (mat == 0) ? q  : (mat == 1) ? k  : v;

    #pragma unroll
    for (int i = 0; i < 4; ++i) {
        int item = i * 256 + tid;
        int row = item >> 3, oct = item & 7;
        union { bf16 h[8]; bf16x8 v8; } u;
        #pragma unroll
        for (int j = 0; j < 8; ++j)
            u.h[j] = __float2bfloat16(ldf(x, (size_t)(m0 + row) * D + oct * 8 + j));
        *(bf16x8*)&Xs[row * QSTR + oct * 8] = u.v8;
    }
    #pragma unroll
    for (int i = 0; i < 4; ++i) {
        int item = i * 256 + tid;
        int n = item & 127, oct = item >> 7;
        union { bf16 h[8]; bf16x8 v8; } u;
        #pragma unroll
        for (int j = 0; j < 8; ++j)
            u.h[j] = __float2bfloat16(ldf(W, (size_t)(oct * 8 + j) * HID + N0 + n));
        *(bf16x8*)&Wt[n * QSTR + oct * 8] = u.v8;
    }
    if (tid < 128) bs[tid] = ldf(bias, N0 + tid);
    __syncthreads();

    const int lane = tid & 63, wave = tid >> 6;
    const int c = lane & 15, quad = lane >> 4;

    bf16x8 af[2][2];
    #pragma unroll
    for (int mg = 0; mg < 2; ++mg)
        #pragma unroll
        for (int kc = 0; kc < 2; ++kc)
            af[mg][kc] = *(const bf16x8*)&Xs[(wave * 32 + mg * 16 + c) * QSTR + kc * 32 + quad * 8];

    f32x4 acc[2][8];
    #pragma unroll
    for (int mg = 0; mg < 2; ++mg)
        #pragma unroll
        for (int ng = 0; ng < 8; ++ng)
            acc[mg][ng] = (f32x4){0.f, 0.f, 0.f, 0.f};

    #pragma unroll
    for (int ng = 0; ng < 8; ++ng) {
        bf16x8 bf0 = *(const bf16x8*)&Wt[(ng * 16 + c) * QSTR + quad * 8];
        bf16x8 bf1 = *(const bf16x8*)&Wt[(ng * 16 + c) * QSTR + 32 + quad * 8];
        #pragma unroll
        for (int mg = 0; mg < 2; ++mg) {
            acc[mg][ng] = __builtin_amdgcn_mfma_f32_16x16x32_bf16(af[mg][0], bf0, acc[mg][ng], 0, 0, 0);
            acc[mg][ng] = __builtin_amdgcn_mfma_f32_16x16x32_bf16(af[mg][1], bf1, acc[mg][ng], 0, 0, 0);
        }
    }

    if (mat == 2) {
        #pragma unroll
        for (int ng = 0; ng < 8; ++ng) {
            int n_g = N0 + ng * 16 + c;
            int h = n_g >> 6, dd = n_g & 63;
            float bb_ = bs[ng * 16 + c];
            #pragma unroll
            for (int mg = 0; mg < 2; ++mg) {
                int row0 = m0 + wave * 32 + mg * 16 + quad * 4;
                int b_ = row0 >> 11, ss = row0 & (S - 1);
                union { bf16 h[4]; bf16x4 v4; } u;
                #pragma unroll
                for (int r = 0; r < 4; ++r)
                    u.h[r] = __float2bfloat16(acc[mg][ng][r] + bb_);
                *(bf16x4*)&dst[((size_t)(b_ * H + h) * D + dd) * S + ss] = u.v4;
            }
        }
    } else {
        #pragma unroll
        for (int ng = 0; ng < 8; ++ng) {
            int n_g = N0 + ng * 16 + c;
            int h = n_g >> 6, dd = n_g & 63;
            float bb_ = bs[ng * 16 + c];
            #pragma unroll
            for (int mg = 0; mg < 2; ++mg) {
                #pragma unroll
                for (int r = 0; r < 4; ++r) {
                    int row = m0 + wave * 32 + mg * 16 + quad * 4 + r;
                    int b_ = row >> 11, ss = row & (S - 1);
                    dst[((size_t)(b_ * H + h) * S + ss) * D + dd] =
                        __float2bfloat16(acc[mg][ng][r] + bb_);
                }
            }
        }
    }
}

__global__ __launch_bounds__(256) void qkv_mfma_kernel(
    const void* x, const void* Wq, const void* bq, const void* Wk,
    const void* bk, const void* Wv, const void* bv,
    bf16* q, bf16* k, bf16* v, const int* flags)
{
    __shared__ bf16 Xs[128 * QSTR];
    __shared__ bf16 Wt[128 * QSTR];
    __shared__ float bs[128];
    if (flags[0])
        qkv_mfma_body<float>((const float*)x, (const float*)Wq, (const float*)bq,
                             (const float*)Wk, (const float*)bk, (const float*)Wv,
                             (const float*)bv, q, k, v, Xs, Wt, bs);
    else
        qkv_mfma_body<bf16>((const bf16*)x, (const bf16*)Wq, (const bf16*)bq,
                            (const bf16*)Wk, (const bf16*)bk, (const bf16*)Wv,
                            (const bf16*)bv, q, k, v, Xs, Wt, bs);
}

// ---------------------------------------------------------------------------
// Kernel 2: flash causal attention, BARRIER-FREE (S^T formulation).
// S^T = K.Q^T: A=K-frag (direct global, L1-shared), B=Q-frag (regs).
//   C-layout: S^T[kcol=16jn+4quad+r][qrow=c] -> each lane owns ONE q-row
//   (wave*16+c); softmax = per-lane reduce + 2 xor-shuffles across quads.
// PV as O^T = V^T.P^T: A=V-frag (direct global from pre-transposed vw),
//   B=P from wave-PRIVATE LDS (4 b64 writes + 2 b128 reads, lgkm fence only).
// No __syncthreads anywhere -> no barrier drain; waves free-run.
// ---------------------------------------------------------------------------
#define BT   64
#define NT   (S / BT)   // 32
#define PST  72
#define MNEG -30000.0f
#define SCL  0.18033688011112042f   // 0.125 * log2(e)

__global__ __launch_bounds__(256, 4) void flash_mfma_kernel(
    const bf16* __restrict__ qg, const bf16* __restrict__ kg,
    const bf16* __restrict__ vg, bf16* __restrict__ og)
{
    __shared__ bf16 Ps[4][16 * PST];   // per-wave P [qrow c][kcol]

    const int tid  = threadIdx.x;
    const int wave = tid >> 6;
    const int lane = tid & 63;
    const int c    = lane & 15;
    const int quad = lane >> 4;
    const int bh   = blockIdx.y;
    const int b_   = bh >> 4, h_ = bh & 15;
    const size_t hbase = (size_t)bh * S * D;   // same stride for kg and vg
    bf16* myPs = &Ps[wave][0];
    const int srow = wave * 16 + c;            // q-row within the 64-tile

    #pragma unroll 1
    for (int phase = 0; phase < 2; ++phase) {
        const int qt = phase ? (NT - 1 - (int)blockIdx.x) : (int)blockIdx.x;
        const int qrow_g = qt * BT + srow;

        bf16x8 qf[2];
        qf[0] = *(const bf16x8*)(qg + hbase + (size_t)qrow_g * D + quad * 8);
        qf[1] = *(const bf16x8*)(qg + hbase + (size_t)qrow_g * D + 32 + quad * 8);

        float m1 = MNEG, l1 = 0.f;
        f32x4 ot[4];
        #pragma unroll
        for (int jn = 0; jn < 4; ++jn) ot[jn] = (f32x4){0.f, 0.f, 0.f, 0.f};

        for (int kt = 0; kt <= qt; ++kt) {
            const bf16* kp = kg + hbase + (size_t)(kt * BT + c) * D;
            const bf16* vp = vg + hbase + (size_t)c * S + kt * BT;

            // ---- S^T = K . Q^T ----
            f32x4 st[4];
            #pragma unroll
            for (int jn = 0; jn < 4; ++jn) {
                bf16x8 kf0 = *(const bf16x8*)(kp + (size_t)jn * 16 * D + quad * 8);
                bf16x8 kf1 = *(const bf16x8*)(kp + (size_t)jn * 16 * D + 32 + quad * 8);
                f32x4 s = {0.f, 0.f, 0.f, 0.f};
                s = __builtin_amdgcn_mfma_f32_16x16x32_bf16(kf0, qf[0], s, 0, 0, 0);
                s = __builtin_amdgcn_mfma_f32_16x16x32_bf16(kf1, qf[1], s, 0, 0, 0);
                st[jn] = s;
            }

            // ---- scale + causal mask (diagonal tile only) ----
            #pragma unroll
            for (int jn = 0; jn < 4; ++jn)
                #pragma unroll
                for (int r = 0; r < 4; ++r) st[jn][r] *= SCL;
            if (kt == qt) {
                #pragma unroll
                for (int jn = 0; jn < 4; ++jn)
                    #pragma unroll
                    for (int r = 0; r < 4; ++r)
                        if (jn * 16 + quad * 4 + r > srow) st[jn][r] = MNEG;
            }

            // ---- per-lane row max, cross-quad reduce (2 shuffles) ----
            float rm = st[0][0];
            #pragma unroll
            for (int jn = 0; jn < 4; ++jn)
                #pragma unroll
                for (int r = 0; r < 4; ++r) rm = fmaxf(rm, st[jn][r]);
            rm = fmaxf(rm, __shfl_xor(rm, 16));
            rm = fmaxf(rm, __shfl_xor(rm, 32));

            float mn = fmaxf(m1, rm);
            float alpha = __builtin_amdgcn_exp2f(m1 - mn);

            float rs = 0.f;
            uint2 pk[4];
            #pragma unroll
            for (int jn = 0; jn < 4; ++jn) {
                float p0 = __builtin_amdgcn_exp2f(st[jn][0] - mn);
                float p1 = __builtin_amdgcn_exp2f(st[jn][1] - mn);
                float p2 = __builtin_amdgcn_exp2f(st[jn][2] - mn);
                float p3 = __builtin_amdgcn_exp2f(st[jn][3] - mn);
                rs += (p0 + p1) + (p2 + p3);
                pk[jn].x = pkbf(p0, p1);
                pk[jn].y = pkbf(p2, p3);
            }
            rs += __shfl_xor(rs, 16);
            rs += __shfl_xor(rs, 32);
            l1 = l1 * alpha + rs;
            m1 = mn;
            #pragma unroll
            for (int jn = 0; jn < 4; ++jn)
                #pragma unroll
                for (int r = 0; r < 4; ++r) ot[jn][r] *= alpha;

            // ---- P -> wave-private LDS (C-layout -> B-layout transpose) ----
            #pragma unroll
            for (int jn = 0; jn < 4; ++jn)
                *(uint2*)&myPs[c * PST + jn * 16 + quad * 4] = pk[jn];
            asm volatile("s_waitcnt lgkmcnt(0)" ::: "memory");

            // ---- O^T += V^T . P^T ----
            #pragma unroll
            for (int kc = 0; kc < 2; ++kc) {
                bf16x8 pf = *(const bf16x8*)&myPs[c * PST + kc * 32 + quad * 8];
                #pragma unroll
                for (int jn = 0; jn < 4; ++jn) {
                    bf16x8 vf = *(const bf16x8*)(vp + (size_t)jn * 16 * S + kc * 32 + quad * 8);
                    ot[jn] = __builtin_amdgcn_mfma_f32_16x16x32_bf16(vf, pf, ot[jn], 0, 0, 0);
                }
            }
        }

        // ---- epilogue: lane owns q-row qrow_g; d = 16jn + 4quad + r ----
        const float inv = 1.f / l1;
        const size_t obase = ((size_t)(b_ * S + qrow_g)) * HID + h_ * 64 + quad * 4;
        #pragma unroll
        for (int jn = 0; jn < 4; ++jn) {
            union { bf16 h[4]; bf16x4 v4; } u;
            #pragma unroll
            for (int r = 0; r < 4; ++r)
                u.h[r] = __float2bfloat16(ot[jn][r] * inv);
            *(bf16x4*)&og[obase + jn * 16] = u.v4;
        }
    }
}

// ---------------------------------------------------------------------------
// Kernel 3: output projection as MFMA GEMM (unchanged from R5).
// ---------------------------------------------------------------------------
template <typename T>
static __device__ __forceinline__ void outproj_mfma_body(
    const bf16* __restrict__ o, const T* __restrict__ Wo,
    const T* __restrict__ bo, void* __restrict__ out, int out_fp32,
    bf16* Os, bf16* Wot, float* bos)
{
    const int tid = threadIdx.x;
    const int m0  = blockIdx.x * 64;
    const int lane = tid & 63, wave = tid >> 6;
    const int c = lane & 15, quad = lane >> 4;

    if (tid < 64) bos[tid] = ldf(bo, tid);

    f32x4 acc[4];
    #pragma unroll
    for (int ng = 0; ng < 4; ++ng) acc[ng] = (f32x4){0.f, 0.f, 0.f, 0.f};

    for (int chunk = 0; chunk < 16; ++chunk) {
        const int k0 = chunk * 64;
        __syncthreads();
        #pragma unroll
        for (int i = 0; i < 2; ++i) {
            int item = i * 256 + tid;
            int row = item >> 3, oct = item & 7;
            *(bf16x8*)&Os[row * QSTR + oct * 8] =
                *(const bf16x8*)(o + (size_t)(m0 + row) * HID + k0 + oct * 8);
        }
        #pragma unroll
        for (int i = 0; i < 2; ++i) {
            int item = i * 256 + tid;
            int n = item & 63, oct = item >> 6;
            union { bf16 h[8]; bf16x8 v8; } u;
            #pragma unroll
            for (int j = 0; j < 8; ++j)
                u.h[j] = __float2bfloat16(ldf(Wo, (size_t)(k0 + oct * 8 + j) * 64 + n));
            *(bf16x8*)&Wot[n * QSTR + oct * 8] = u.v8;
        }
        __syncthreads();

        bf16x8 a0 = *(const bf16x8*)&Os[(wave * 16 + c) * QSTR + quad * 8];
        bf16x8 a1 = *(const bf16x8*)&Os[(wave * 16 + c) * QSTR + 32 + quad * 8];
        #pragma unroll
        for (int ng = 0; ng < 4; ++ng) {
            bf16x8 b0 = *(const bf16x8*)&Wot[(ng * 16 + c) * QSTR + quad * 8];
            bf16x8 b1 = *(const bf16x8*)&Wot[(ng * 16 + c) * QSTR + 32 + quad * 8];
            acc[ng] = __builtin_amdgcn_mfma_f32_16x16x32_bf16(a0, b0, acc[ng], 0, 0, 0);
            acc[ng] = __builtin_amdgcn_mfma_f32_16x16x32_bf16(a1, b1, acc[ng], 0, 0, 0);
        }
    }

    #pragma unroll
    for (int ng = 0; ng < 4; ++ng) {
        int n = ng * 16 + c;
        float bb_ = bos[n];
        #pragma unroll
        for (int r = 0; r < 4; ++r) {
            int row = m0 + wave * 16 + quad * 4 + r;
            float sum = acc[ng][r] + bb_;
            size_t oidx = (size_t)row * 64 + n;
            if (out_fp32) ((float*)out)[oidx] = sum;
            else          ((bf16*)out)[oidx]  = __float2bfloat16(sum);
        }
    }
}

__global__ __launch_bounds__(256) void out_proj_mfma_kernel(
    const bf16* o, const void* Wo, const void* bo, void* out,
    const int* flags)
{
    __shared__ bf16 Os[64 * QSTR];
    __shared__ bf16 Wot[64 * QSTR];
    __shared__ float bos[64];
    if (flags[0])
        outproj_mfma_body<float>(o, (const float*)Wo, (const float*)bo, out, 1,
                                 Os, Wot, bos);
    else
        outproj_mfma_body<bf16>(o, (const bf16*)Wo, (const bf16*)bo, out, 0,
                                Os, Wot, bos);
}

// ---------------------------------------------------------------------------
extern "C" void kernel_launch(void* const* d_in, const int* in_sizes, int n_in,
                              void* d_out, int out_size, void* d_ws, size_t ws_size,
                              hipStream_t stream)
{
    char* ws = (char*)d_ws;
    const size_t qkv_bytes = (size_t)B * S * HID * sizeof(bf16);  // 16 MiB each
    bf16* qw = (bf16*)(ws);
    bf16* kw = (bf16*)(ws + qkv_bytes);
    bf16* vw = (bf16*)(ws + 2 * qkv_bytes);   // transposed [B][H][D][S]
    bf16* ow = (bf16*)(ws + 3 * qkv_bytes);
    int* flags = (int*)(ws + 4 * qkv_bytes);

    detect_kernel<<<9, 256, 0, stream>>>(d_in[0], d_in[1], d_in[2], d_in[3],
                                         d_in[4], d_in[5], d_in[6], d_in[7],
                                         d_in[8], flags);

    qkv_mfma_kernel<<<dim3(B * S / 128, 24), 256, 0, stream>>>(
        d_in[0], d_in[1], d_in[2], d_in[3], d_in[4], d_in[5], d_in[6],
        qw, kw, vw, flags);

    flash_mfma_kernel<<<dim3(NT / 2, B * H), 256, 0, stream>>>(qw, kw, vw, ow);

    out_proj_mfma_kernel<<<dim3(B * S / 64), 256, 0, stream>>>(ow, d_in[7],
                                                               d_in[8], d_out,
                                                               flags);
}

// Round 10
// 195.686 us; speedup vs baseline: 1.7607x; 1.7607x over previous
//
#include <hip/hip_runtime.h>
#include <hip/hip_bf16.h>

#define B 4
#define S 2048
#define H 16
#define D 64
#define HID 1024

typedef __hip_bfloat16 bf16;
typedef __attribute__((ext_vector_type(8))) short bf16x8;
typedef __attribute__((ext_vector_type(4))) short bf16x4;
typedef __attribute__((ext_vector_type(4))) float f32x4;

static __device__ __forceinline__ float b2f(bf16 v) { return __bfloat162float(v); }
static __device__ __forceinline__ float ldf(const float* p, size_t i) { return p[i]; }
static __device__ __forceinline__ float ldf(const bf16* p, size_t i) { return b2f(p[i]); }

static __device__ __forceinline__ unsigned pkbf(float a, float b) {
    union { bf16 h; unsigned short u; } ua, ub;
    ua.h = __float2bfloat16(a);
    ub.h = __float2bfloat16(b);
    return (unsigned)ua.u | ((unsigned)ub.u << 16);
}

// ---------------------------------------------------------------------------
// Kernel 0: dtype detector (proven R2-R9). flags[i]=1 -> fp32.
// ---------------------------------------------------------------------------
__global__ __launch_bounds__(256) void detect_kernel(
    const void* p0, const void* p1, const void* p2, const void* p3,
    const void* p4, const void* p5, const void* p6, const void* p7,
    const void* p8, int* flags)
{
    __shared__ int cnt;
    const void* ps[9] = {p0, p1, p2, p3, p4, p5, p6, p7, p8};
    const int   ns[9] = {B * S * D, D * HID, HID, D * HID, HID,
                         D * HID, HID, HID * D, D};
    const int i = blockIdx.x;
    const bf16* p = (const bf16*)ps[i];
    int n = ns[i];
    if (n > 2048) n = 2048;
    if (threadIdx.x == 0) cnt = 0;
    __syncthreads();
    int wild = 0;
    for (int t = threadIdx.x; t < n; t += 256) {
        float f = b2f(p[t]);
        if (!(f == f) || fabsf(f) > 1e4f) wild++;
    }
    if (wild) atomicAdd(&cnt, wild);
    __syncthreads();
    if (threadIdx.x == 0) flags[i] = (cnt >= 2) ? 1 : 0;
}

// ---------------------------------------------------------------------------
// Kernel 1: QKV projection as MFMA GEMM (unchanged from R8/R9).
// Q,K stored [B][H][S][D]; V stored TRANSPOSED [B][H][D][S].
// ---------------------------------------------------------------------------
#define QSTR 72

template <typename T>
static __device__ __forceinline__ void qkv_mfma_body(
    const T* __restrict__ x,
    const T* __restrict__ Wq, const T* __restrict__ bq,
    const T* __restrict__ Wk, const T* __restrict__ bk,
    const T* __restrict__ Wv, const T* __restrict__ bv,
    bf16* __restrict__ q, bf16* __restrict__ k, bf16* __restrict__ v,
    bf16* Xs, bf16* Wt, float* bs)
{
    const int tid = threadIdx.x;
    const int mat = blockIdx.y >> 3;
    const int N0  = (blockIdx.y & 7) * 128;
    const int m0  = blockIdx.x * 128;

    const T* W    = (mat == 0) ? Wq : (mat == 1) ? Wk : Wv;
    const T* bias = (mat == 0) ? bq : (mat == 1) ? bk : bv;
    bf16*    dst  = (mat == 0) ? q  : (mat == 1) ? k  : v;

    #pragma unroll
    for (int i = 0; i < 4; ++i) {
        int item = i * 256 + tid;
        int row = item >> 3, oct = item & 7;
        union { bf16 h[8]; bf16x8 v8; } u;
        #pragma unroll
        for (int j = 0; j < 8; ++j)
            u.h[j] = __float2bfloat16(ldf(x, (size_t)(m0 + row) * D + oct * 8 + j));
        *(bf16x8*)&Xs[row * QSTR + oct * 8] = u.v8;
    }
    #pragma unroll
    for (int i = 0; i < 4; ++i) {
        int item = i * 256 + tid;
        int n = item & 127, oct = item >> 7;
        union { bf16 h[8]; bf16x8 v8; } u;
        #pragma unroll
        for (int j = 0; j < 8; ++j)
            u.h[j] = __float2bfloat16(ldf(W, (size_t)(oct * 8 + j) * HID + N0 + n));
        *(bf16x8*)&Wt[n * QSTR + oct * 8] = u.v8;
    }
    if (tid < 128) bs[tid] = ldf(bias, N0 + tid);
    __syncthreads();

    const int lane = tid & 63, wave = tid >> 6;
    const int c = lane & 15, quad = lane >> 4;

    bf16x8 af[2][2];
    #pragma unroll
    for (int mg = 0; mg < 2; ++mg)
        #pragma unroll
        for (int kc = 0; kc < 2; ++kc)
            af[mg][kc] = *(const bf16x8*)&Xs[(wave * 32 + mg * 16 + c) * QSTR + kc * 32 + quad * 8];

    f32x4 acc[2][8];
    #pragma unroll
    for (int mg = 0; mg < 2; ++mg)
        #pragma unroll
        for (int ng = 0; ng < 8; ++ng)
            acc[mg][ng] = (f32x4){0.f, 0.f, 0.f, 0.f};

    #pragma unroll
    for (int ng = 0; ng < 8; ++ng) {
        bf16x8 bf0 = *(const bf16x8*)&Wt[(ng * 16 + c) * QSTR + quad * 8];
        bf16x8 bf1 = *(const bf16x8*)&Wt[(ng * 16 + c) * QSTR + 32 + quad * 8];
        #pragma unroll
        for (int mg = 0; mg < 2; ++mg) {
            acc[mg][ng] = __builtin_amdgcn_mfma_f32_16x16x32_bf16(af[mg][0], bf0, acc[mg][ng], 0, 0, 0);
            acc[mg][ng] = __builtin_amdgcn_mfma_f32_16x16x32_bf16(af[mg][1], bf1, acc[mg][ng], 0, 0, 0);
        }
    }

    if (mat == 2) {
        #pragma unroll
        for (int ng = 0; ng < 8; ++ng) {
            int n_g = N0 + ng * 16 + c;
            int h = n_g >> 6, dd = n_g & 63;
            float bb_ = bs[ng * 16 + c];
            #pragma unroll
            for (int mg = 0; mg < 2; ++mg) {
                int row0 = m0 + wave * 32 + mg * 16 + quad * 4;
                int b_ = row0 >> 11, ss = row0 & (S - 1);
                union { bf16 h[4]; bf16x4 v4; } u;
                #pragma unroll
                for (int r = 0; r < 4; ++r)
                    u.h[r] = __float2bfloat16(acc[mg][ng][r] + bb_);
                *(bf16x4*)&dst[((size_t)(b_ * H + h) * D + dd) * S + ss] = u.v4;
            }
        }
    } else {
        #pragma unroll
        for (int ng = 0; ng < 8; ++ng) {
            int n_g = N0 + ng * 16 + c;
            int h = n_g >> 6, dd = n_g & 63;
            float bb_ = bs[ng * 16 + c];
            #pragma unroll
            for (int mg = 0; mg < 2; ++mg) {
                #pragma unroll
                for (int r = 0; r < 4; ++r) {
                    int row = m0 + wave * 32 + mg * 16 + quad * 4 + r;
                    int b_ = row >> 11, ss = row & (S - 1);
                    dst[((size_t)(b_ * H + h) * S + ss) * D + dd] =
                        __float2bfloat16(acc[mg][ng][r] + bb_);
                }
            }
        }
    }
}

__global__ __launch_bounds__(256) void qkv_mfma_kernel(
    const void* x, const void* Wq, const void* bq, const void* Wk,
    const void* bk, const void* Wv, const void* bv,
    bf16* q, bf16* k, bf16* v, const int* flags)
{
    __shared__ bf16 Xs[128 * QSTR];
    __shared__ bf16 Wt[128 * QSTR];
    __shared__ float bs[128];
    if (flags[0])
        qkv_mfma_body<float>((const float*)x, (const float*)Wq, (const float*)bq,
                             (const float*)Wk, (const float*)bk, (const float*)Wv,
                             (const float*)bv, q, k, v, Xs, Wt, bs);
    else
        qkv_mfma_body<bf16>((const bf16*)x, (const bf16*)Wq, (const bf16*)bq,
                            (const bf16*)Wk, (const bf16*)bk, (const bf16*)Wv,
                            (const bf16*)bv, q, k, v, Xs, Wt, bs);
}

// ---------------------------------------------------------------------------
// Kernel 2: flash causal attention — HYBRID:
//  * R8 skeleton: paired triangular grid (uniform blocks), K/V^T LDS staging,
//    register prefetch of tile kt+1 overlapping compute (proven 150us).
//  * R9 math core: S^T = K.Q^T (A=K-frag from LDS, B=Q regs) -> each lane
//    owns ONE q-row; softmax = per-lane reduce + 2 xor-shuffles (vs 40);
//    P^T via wave-private LDS (4 b64 writes, 2 b128 reads, lgkm fence only);
//    O^T = V^T.P^T; per-lane epilogue (proven absmax-identical in R9).
// R9 lesson: direct-global MFMA operands stall on vmcnt — stage via LDS.
// ---------------------------------------------------------------------------
#define BT   64
#define NT   (S / BT)   // 32
#define KSTR 72
#define PST  72
#define MNEG -30000.0f
#define SCL  0.18033688011112042f   // 0.125 * log2(e)

__global__ __launch_bounds__(256) void flash_mfma_kernel(
    const bf16* __restrict__ qg, const bf16* __restrict__ kg,
    const bf16* __restrict__ vg, bf16* __restrict__ og)
{
    __shared__ bf16 Ks[BT * KSTR];     // K tile [krow][d]
    __shared__ bf16 Vt[BT * KSTR];     // V^T tile [d][krow]
    __shared__ bf16 Ps[4][16 * PST];   // per-wave P [qrow c][kcol]

    const int tid  = threadIdx.x;
    const int wave = tid >> 6;
    const int lane = tid & 63;
    const int c    = lane & 15;
    const int quad = lane >> 4;
    const int bh   = blockIdx.y;
    const int b_   = bh >> 4, h_ = bh & 15;
    const size_t hbase = (size_t)bh * S * D;
    bf16* myPs = &Ps[wave][0];
    const int srow = wave * 16 + c;          // this lane's q-row in the tile

    // staging coordinates (K rows / V^T rows)
    const int sr0 = tid >> 3,         sc0 = (tid & 7) * 8;
    const int sr1 = (tid + 256) >> 3, sc1 = sc0;

    #pragma unroll 1
    for (int phase = 0; phase < 2; ++phase) {
        const int qt = phase ? (NT - 1 - (int)blockIdx.x) : (int)blockIdx.x;
        const int qrow_g = qt * BT + srow;

        bf16x8 qf[2];
        qf[0] = *(const bf16x8*)(qg + hbase + (size_t)qrow_g * D + quad * 8);
        qf[1] = *(const bf16x8*)(qg + hbase + (size_t)qrow_g * D + 32 + quad * 8);

        // ---- prefetch tile 0 into registers ----
        bf16x8 kreg0, kreg1, vreg0, vreg1;
        kreg0 = *(const bf16x8*)(kg + hbase + (size_t)sr0 * D + sc0);
        kreg1 = *(const bf16x8*)(kg + hbase + (size_t)sr1 * D + sc1);
        vreg0 = *(const bf16x8*)(vg + hbase + (size_t)sr0 * S + sc0);
        vreg1 = *(const bf16x8*)(vg + hbase + (size_t)sr1 * S + sc1);

        float m1 = MNEG, l1 = 0.f;
        f32x4 ot[4];
        #pragma unroll
        for (int jn = 0; jn < 4; ++jn) ot[jn] = (f32x4){0.f, 0.f, 0.f, 0.f};

        for (int kt = 0; kt <= qt; ++kt) {
            __syncthreads();   // prior tile's LDS reads complete
            *(bf16x8*)&Ks[sr0 * KSTR + sc0] = kreg0;
            *(bf16x8*)&Ks[sr1 * KSTR + sc1] = kreg1;
            *(bf16x8*)&Vt[sr0 * KSTR + sc0] = vreg0;
            *(bf16x8*)&Vt[sr1 * KSTR + sc1] = vreg1;
            __syncthreads();   // tile visible

            // ---- prefetch kt+1 (latency overlaps compute below) ----
            if (kt < qt) {
                const int nb = (kt + 1) * BT;
                kreg0 = *(const bf16x8*)(kg + hbase + (size_t)(nb + sr0) * D + sc0);
                kreg1 = *(const bf16x8*)(kg + hbase + (size_t)(nb + sr1) * D + sc1);
                vreg0 = *(const bf16x8*)(vg + hbase + (size_t)sr0 * S + nb + sc0);
                vreg1 = *(const bf16x8*)(vg + hbase + (size_t)sr1 * S + nb + sc1);
            }

            // ---- S^T = K . Q^T (lane owns q-row c, kcols 16jn+4quad+r) ----
            f32x4 st[4];
            #pragma unroll
            for (int jn = 0; jn < 4; ++jn) {
                bf16x8 kf0 = *(const bf16x8*)&Ks[(jn * 16 + c) * KSTR + quad * 8];
                bf16x8 kf1 = *(const bf16x8*)&Ks[(jn * 16 + c) * KSTR + 32 + quad * 8];
                f32x4 s = {0.f, 0.f, 0.f, 0.f};
                s = __builtin_amdgcn_mfma_f32_16x16x32_bf16(kf0, qf[0], s, 0, 0, 0);
                s = __builtin_amdgcn_mfma_f32_16x16x32_bf16(kf1, qf[1], s, 0, 0, 0);
                st[jn] = s;
            }

            // ---- scale + causal mask (diagonal tile only) ----
            #pragma unroll
            for (int jn = 0; jn < 4; ++jn)
                #pragma unroll
                for (int r = 0; r < 4; ++r) st[jn][r] *= SCL;
            if (kt == qt) {
                #pragma unroll
                for (int jn = 0; jn < 4; ++jn)
                    #pragma unroll
                    for (int r = 0; r < 4; ++r)
                        if (jn * 16 + quad * 4 + r > srow) st[jn][r] = MNEG;
            }

            // ---- per-lane softmax, cross-quad reduce (2 shuffles each) ----
            float rm = st[0][0];
            #pragma unroll
            for (int jn = 0; jn < 4; ++jn)
                #pragma unroll
                for (int r = 0; r < 4; ++r) rm = fmaxf(rm, st[jn][r]);
            rm = fmaxf(rm, __shfl_xor(rm, 16));
            rm = fmaxf(rm, __shfl_xor(rm, 32));

            float mn = fmaxf(m1, rm);
            float alpha = __builtin_amdgcn_exp2f(m1 - mn);

            float rs = 0.f;
            uint2 pk[4];
            #pragma unroll
            for (int jn = 0; jn < 4; ++jn) {
                float p0 = __builtin_amdgcn_exp2f(st[jn][0] - mn);
                float p1 = __builtin_amdgcn_exp2f(st[jn][1] - mn);
                float p2 = __builtin_amdgcn_exp2f(st[jn][2] - mn);
                float p3 = __builtin_amdgcn_exp2f(st[jn][3] - mn);
                rs += (p0 + p1) + (p2 + p3);
                pk[jn].x = pkbf(p0, p1);
                pk[jn].y = pkbf(p2, p3);
            }
            rs += __shfl_xor(rs, 16);
            rs += __shfl_xor(rs, 32);
            l1 = l1 * alpha + rs;
            m1 = mn;
            #pragma unroll
            for (int jn = 0; jn < 4; ++jn)
                #pragma unroll
                for (int r = 0; r < 4; ++r) ot[jn][r] *= alpha;

            // ---- P -> wave-private LDS (C-layout -> B-layout) ----
            #pragma unroll
            for (int jn = 0; jn < 4; ++jn)
                *(uint2*)&myPs[c * PST + jn * 16 + quad * 4] = pk[jn];
            asm volatile("s_waitcnt lgkmcnt(0)" ::: "memory");

            // ---- O^T += V^T . P^T ----
            #pragma unroll
            for (int kc = 0; kc < 2; ++kc) {
                bf16x8 pf = *(const bf16x8*)&myPs[c * PST + kc * 32 + quad * 8];
                #pragma unroll
                for (int jn = 0; jn < 4; ++jn) {
                    bf16x8 vf = *(const bf16x8*)&Vt[(jn * 16 + c) * KSTR + kc * 32 + quad * 8];
                    ot[jn] = __builtin_amdgcn_mfma_f32_16x16x32_bf16(vf, pf, ot[jn], 0, 0, 0);
                }
            }
        }

        // ---- epilogue: lane owns q-row qrow_g; d = 16jn + 4quad + r ----
        const float inv = 1.f / l1;
        const size_t obase = ((size_t)(b_ * S + qrow_g)) * HID + h_ * 64 + quad * 4;
        #pragma unroll
        for (int jn = 0; jn < 4; ++jn) {
            union { bf16 h[4]; bf16x4 v4; } u;
            #pragma unroll
            for (int r = 0; r < 4; ++r)
                u.h[r] = __float2bfloat16(ot[jn][r] * inv);
            *(bf16x4*)&og[obase + jn * 16] = u.v4;
        }
    }
}

// ---------------------------------------------------------------------------
// Kernel 3: output projection as MFMA GEMM (unchanged from R5).
// ---------------------------------------------------------------------------
template <typename T>
static __device__ __forceinline__ void outproj_mfma_body(
    const bf16* __restrict__ o, const T* __restrict__ Wo,
    const T* __restrict__ bo, void* __restrict__ out, int out_fp32,
    bf16* Os, bf16* Wot, float* bos)
{
    const int tid = threadIdx.x;
    const int m0  = blockIdx.x * 64;
    const int lane = tid & 63, wave = tid >> 6;
    const int c = lane & 15, quad = lane >> 4;

    if (tid < 64) bos[tid] = ldf(bo, tid);

    f32x4 acc[4];
    #pragma unroll
    for (int ng = 0; ng < 4; ++ng) acc[ng] = (f32x4){0.f, 0.f, 0.f, 0.f};

    for (int chunk = 0; chunk < 16; ++chunk) {
        const int k0 = chunk * 64;
        __syncthreads();
        #pragma unroll
        for (int i = 0; i < 2; ++i) {
            int item = i * 256 + tid;
            int row = item >> 3, oct = item & 7;
            *(bf16x8*)&Os[row * QSTR + oct * 8] =
                *(const bf16x8*)(o + (size_t)(m0 + row) * HID + k0 + oct * 8);
        }
        #pragma unroll
        for (int i = 0; i < 2; ++i) {
            int item = i * 256 + tid;
            int n = item & 63, oct = item >> 6;
            union { bf16 h[8]; bf16x8 v8; } u;
            #pragma unroll
            for (int j = 0; j < 8; ++j)
                u.h[j] = __float2bfloat16(ldf(Wo, (size_t)(k0 + oct * 8 + j) * 64 + n));
            *(bf16x8*)&Wot[n * QSTR + oct * 8] = u.v8;
        }
        __syncthreads();

        bf16x8 a0 = *(const bf16x8*)&Os[(wave * 16 + c) * QSTR + quad * 8];
        bf16x8 a1 = *(const bf16x8*)&Os[(wave * 16 + c) * QSTR + 32 + quad * 8];
        #pragma unroll
        for (int ng = 0; ng < 4; ++ng) {
            bf16x8 b0 = *(const bf16x8*)&Wot[(ng * 16 + c) * QSTR + quad * 8];
            bf16x8 b1 = *(const bf16x8*)&Wot[(ng * 16 + c) * QSTR + 32 + quad * 8];
            acc[ng] = __builtin_amdgcn_mfma_f32_16x16x32_bf16(a0, b0, acc[ng], 0, 0, 0);
            acc[ng] = __builtin_amdgcn_mfma_f32_16x16x32_bf16(a1, b1, acc[ng], 0, 0, 0);
        }
    }

    #pragma unroll
    for (int ng = 0; ng < 4; ++ng) {
        int n = ng * 16 + c;
        float bb_ = bos[n];
        #pragma unroll
        for (int r = 0; r < 4; ++r) {
            int row = m0 + wave * 16 + quad * 4 + r;
            float sum = acc[ng][r] + bb_;
            size_t oidx = (size_t)row * 64 + n;
            if (out_fp32) ((float*)out)[oidx] = sum;
            else          ((bf16*)out)[oidx]  = __float2bfloat16(sum);
        }
    }
}

__global__ __launch_bounds__(256) void out_proj_mfma_kernel(
    const bf16* o, const void* Wo, const void* bo, void* out,
    const int* flags)
{
    __shared__ bf16 Os[64 * QSTR];
    __shared__ bf16 Wot[64 * QSTR];
    __shared__ float bos[64];
    if (flags[0])
        outproj_mfma_body<float>(o, (const float*)Wo, (const float*)bo, out, 1,
                                 Os, Wot, bos);
    else
        outproj_mfma_body<bf16>(o, (const bf16*)Wo, (const bf16*)bo, out, 0,
                                Os, Wot, bos);
}

// ---------------------------------------------------------------------------
extern "C" void kernel_launch(void* const* d_in, const int* in_sizes, int n_in,
                              void* d_out, int out_size, void* d_ws, size_t ws_size,
                              hipStream_t stream)
{
    char* ws = (char*)d_ws;
    const size_t qkv_bytes = (size_t)B * S * HID * sizeof(bf16);  // 16 MiB each
    bf16* qw = (bf16*)(ws);
    bf16* kw = (bf16*)(ws + qkv_bytes);
    bf16* vw = (bf16*)(ws + 2 * qkv_bytes);   // transposed [B][H][D][S]
    bf16* ow = (bf16*)(ws + 3 * qkv_bytes);
    int* flags = (int*)(ws + 4 * qkv_bytes);

    detect_kernel<<<9, 256, 0, stream>>>(d_in[0], d_in[1], d_in[2], d_in[3],
                                         d_in[4], d_in[5], d_in[6], d_in[7],
                                         d_in[8], flags);

    qkv_mfma_kernel<<<dim3(B * S / 128, 24), 256, 0, stream>>>(
        d_in[0], d_in[1], d_in[2], d_in[3], d_in[4], d_in[5], d_in[6],
        qw, kw, vw, flags);

    flash_mfma_kernel<<<dim3(NT / 2, B * H), 256, 0, stream>>>(qw, kw, vw, ow);

    out_proj_mfma_kernel<<<dim3(B * S / 64), 256, 0, stream>>>(ow, d_in[7],
                                                               d_in[8], d_out,
                                                               flags);
}